// Round 2
// baseline (340.903 us; speedup 1.0000x reference)
//
#include <hip/hip_runtime.h>
#include <hip/hip_bf16.h>
#include <math.h>

#define E_DIM 128
#define R_DIM 128
#define REG_LAMBDA 1e-5f

// One WAVE (64 threads) per sample m. Thread t owns output columns {2t, 2t+1}.
// h/pos/neg/rel rows are wave-uniform -> forced to the SGPR/s_load path via
// readfirstlane, so the inner loop is 6 VALU FMA + 1 global dwordx2 per k.
__global__ void __launch_bounds__(64)
kge_sample_kernel(const int* __restrict__ h_idx, const int* __restrict__ r_idx,
                  const int* __restrict__ pt_idx, const int* __restrict__ nt_idx,
                  const float* __restrict__ ent,   // (N_ENT, 128)
                  const float* __restrict__ rel,   // (64, 128)
                  const float* __restrict__ W,     // (64, 128, 128)
                  float* __restrict__ per_sample,  // (M,)
                  int M)
{
    int m = blockIdx.x;
    if (m >= M) return;
    int t = threadIdx.x;  // 0..63

    // Wave-uniform indices -> SGPRs
    int hi = __builtin_amdgcn_readfirstlane(h_idx[m]);
    int ri = __builtin_amdgcn_readfirstlane(r_idx[m]);
    int pi = __builtin_amdgcn_readfirstlane(pt_idx[m]);
    int ni = __builtin_amdgcn_readfirstlane(nt_idx[m]);

    const float* __restrict__ hrow = ent + (size_t)hi * E_DIM;
    const float* __restrict__ prow = ent + (size_t)pi * E_DIM;
    const float* __restrict__ nrow = ent + (size_t)ni * E_DIM;
    const float* __restrict__ rrow = rel + (size_t)ri * R_DIM;

    const float2* __restrict__ W2 = (const float2*)(W + (size_t)ri * (E_DIM * R_DIM));

    float ah0 = 0.f, ah1 = 0.f, ap0 = 0.f, ap1 = 0.f, an0 = 0.f, an1 = 0.f;

#pragma unroll 16
    for (int e = 0; e < E_DIM; ++e) {
        float2 w = W2[e * (R_DIM / 2) + t];   // coalesced 512B per wave
        float he = hrow[e];                    // uniform -> s_load (scalar pipe)
        float pe = prow[e];
        float ne = nrow[e];
        ah0 = fmaf(he, w.x, ah0);  ah1 = fmaf(he, w.y, ah1);
        ap0 = fmaf(pe, w.x, ap0);  ap1 = fmaf(pe, w.y, ap1);
        an0 = fmaf(ne, w.x, an0);  an1 = fmaf(ne, w.y, an1);
    }

    // per-lane pieces: this lane's 2 columns of the scores
    float2 re2 = ((const float2*)rrow)[t];
    float dp0 = ah0 + re2.x - ap0, dp1 = ah1 + re2.y - ap1;
    float dn0 = ah0 + re2.x - an0, dn1 = ah1 + re2.y - an1;
    float pos = dp0 * dp0 + dp1 * dp1;
    float neg = dn0 * dn0 + dn1 * dn1;

    // regularizer pieces: this lane's 2 elements of each row
    float2 he2 = ((const float2*)hrow)[t];
    float2 pe2 = ((const float2*)prow)[t];
    float2 ne2 = ((const float2*)nrow)[t];
    float reg = he2.x * he2.x + he2.y * he2.y
              + pe2.x * pe2.x + pe2.y * pe2.y
              + ne2.x * ne2.x + ne2.y * ne2.y
              + re2.x * re2.x + re2.y * re2.y;

    // wave64 shuffle reduce
#pragma unroll
    for (int off = 32; off > 0; off >>= 1) {
        pos += __shfl_down(pos, off);
        neg += __shfl_down(neg, off);
        reg += __shfl_down(reg, off);
    }

    if (t == 0) {
        float diff = 0.5f * (pos - neg);           // pos_score - neg_score
        float z = -diff;                           // -log_sigmoid(diff) = softplus(-diff)
        float sp_v = fmaxf(z, 0.f) + log1pf(expf(-fabsf(z)));
        per_sample[m] = sp_v + REG_LAMBDA * 0.5f * reg;
    }
}

// Single-block final reduction -> mean
__global__ void __launch_bounds__(256)
kge_reduce_kernel(const float* __restrict__ per_sample, float* __restrict__ out, int M)
{
    int t = threadIdx.x;
    float s = 0.f;
    for (int i = t; i < M; i += 256) s += per_sample[i];
#pragma unroll
    for (int off = 32; off > 0; off >>= 1) s += __shfl_down(s, off);
    __shared__ float part[4];
    if ((t & 63) == 0) part[t >> 6] = s;
    __syncthreads();
    if (t == 0) out[0] = (part[0] + part[1] + part[2] + part[3]) / (float)M;
}

extern "C" void kernel_launch(void* const* d_in, const int* in_sizes, int n_in,
                              void* d_out, int out_size, void* d_ws, size_t ws_size,
                              hipStream_t stream)
{
    const int*   h_idx  = (const int*)d_in[0];
    const int*   r_idx  = (const int*)d_in[1];
    const int*   pt_idx = (const int*)d_in[2];
    const int*   nt_idx = (const int*)d_in[3];
    const float* ent    = (const float*)d_in[4];
    const float* rel    = (const float*)d_in[5];
    const float* W      = (const float*)d_in[6];
    float* out = (float*)d_out;

    int M = in_sizes[0];
    float* per_sample = (float*)d_ws;  // M floats

    kge_sample_kernel<<<M, 64, 0, stream>>>(h_idx, r_idx, pt_idx, nt_idx,
                                            ent, rel, W, per_sample, M);
    kge_reduce_kernel<<<1, 256, 0, stream>>>(per_sample, out, M);
}